// Round 8
// baseline (269.826 us; speedup 1.0000x reference)
//
#include <hip/hip_runtime.h>

#define NN 100000
#define NE 1600000
#define DD 128
#define CAP 48

constexpr int NP = 100096;

#define DEGF_BLKS 2048
#define CAST_BLKS 1600
#define WT2_BLKS  32
#define MISC_BLKS (DEGF_BLKS + CAST_BLKS + WT2_BLKS)

typedef __attribute__((ext_vector_type(8))) short bf16x8;
typedef __attribute__((ext_vector_type(4))) float f32x4;

__device__ inline unsigned short f2bf(float f) {
  union { float f; unsigned u; } v; v.f = f;
  unsigned r = (v.u + 0x7FFF + ((v.u >> 16) & 1)) >> 16;
  return (unsigned short)r;
}

// ---- K1 fused: blocks [0,2048) degree+bucket-fill; [2048,3648) x->bf16 cast;
//      [3648,3680) weight transpose ----
__global__ __launch_bounds__(256) void k_misc(
    const int* __restrict__ row, const int* __restrict__ col,
    const float* __restrict__ ew, const float* __restrict__ x,
    const float* __restrict__ Wl, const float* __restrict__ Wg,
    unsigned long long* __restrict__ degcnt, unsigned long long* __restrict__ edgeA,
    unsigned short* __restrict__ xb, unsigned short* __restrict__ WT2) {
  int b = blockIdx.x;
  if (b < DEGF_BLKS) {
    for (int e = b * 256 + threadIdx.x; e < NE; e += DEGF_BLKS * 256) {
      int c = col[e];
      float w = ew[e];
      unsigned long long fx = (unsigned long long)(w * 1073741824.0f + 0.5f);
      unsigned long long old = atomicAdd(&degcnt[c], (1ULL << 48) | fx);
      int k = (int)(old >> 48);
      if (k < CAP)
        edgeA[(size_t)c * CAP + k] =
            ((unsigned long long)__float_as_uint(w) << 32) | (unsigned)row[e];
    }
  } else if (b < DEGF_BLKS + CAST_BLKS) {
    int bb = b - DEGF_BLKS;
    const int total8 = NN * DD / 8;
    for (int i = bb * 256 + threadIdx.x; i < total8; i += CAST_BLKS * 256) {
      float4 a = *(const float4*)&x[i * 8];
      float4 q = *(const float4*)&x[i * 8 + 4];
      unsigned short o[8] = {f2bf(a.x), f2bf(a.y), f2bf(a.z), f2bf(a.w),
                             f2bf(q.x), f2bf(q.y), f2bf(q.z), f2bf(q.w)};
      *(uint4*)&xb[i * 8] = *(uint4*)o;
    }
  } else {
    int bb = b - DEGF_BLKS - CAST_BLKS;      // 0..31
    int j = bb * 4 + (threadIdx.x >> 6);     // 0..127
    int l = threadIdx.x & 63;
    for (int k = l; k < 256; k += 64) {
      const float* W = (k < DD) ? Wl : Wg;
      WT2[j * 256 + k] = f2bf(W[(k & (DD - 1)) * DD + j]);
    }
  }
}

// ---- K2: dis = rsqrt(weighted deg) ----
__global__ __launch_bounds__(256) void k_dis(const unsigned long long* __restrict__ degcnt,
    float* __restrict__ dis) {
  int i = blockIdx.x * 256 + threadIdx.x;
  if (i < NN) {
    unsigned long long v = degcnt[i];
    float d = (float)(v & 0xFFFFFFFFFFFFULL) * (1.0f / 1073741824.0f);
    dis[i] = (d > 0.0f) ? rsqrtf(d) : 0.0f;
  }
}

// ---- K3: gather y[c] = dis[c] * sum_k ew_k * dis[src_k] * xb[src_k] -> bf16 ----
// one wave per dst; 4 edges/iter via 16-lane groups, 16B row loads, 2x unroll
__global__ __launch_bounds__(256) void k_gather(const unsigned short* __restrict__ xb,
    const unsigned long long* __restrict__ degcnt, const float* __restrict__ dis,
    const unsigned long long* __restrict__ edgeA, unsigned short* __restrict__ yb) {
  int wid = (blockIdx.x * blockDim.x + threadIdx.x) >> 6;
  int lane = threadIdx.x & 63;
  if (wid >= NN) return;
  int grp = lane >> 4, l16 = lane & 15;
  int cnt = (int)(degcnt[wid] >> 48);
  if (cnt > CAP) cnt = CAP;
  const unsigned long long* bucket = edgeA + (size_t)wid * CAP;
  float acc[8] = {};
  for (int i = 0; i < cnt; i += 8) {
    int ja = i + grp, jb = i + 4 + grp;
    int sa = 0, sb = 0;
    float wa = 0.f, wb = 0.f;
    if (ja < cnt) {
      unsigned long long ev = bucket[ja];
      sa = (int)(unsigned)ev;
      wa = __uint_as_float((unsigned)(ev >> 32)) * dis[sa];
    }
    if (jb < cnt) {
      unsigned long long ev = bucket[jb];
      sb = (int)(unsigned)ev;
      wb = __uint_as_float((unsigned)(ev >> 32)) * dis[sb];
    }
    uint4 ha = *(const uint4*)&xb[(size_t)sa * DD + l16 * 8];
    uint4 hb = *(const uint4*)&xb[(size_t)sb * DD + l16 * 8];
    union { uint4 v; unsigned u[4]; } qa, qb;
    qa.v = ha; qb.v = hb;
    #pragma unroll
    for (int k = 0; k < 4; k++) {
      union { unsigned u; float f; } lo, hi;
      lo.u = qa.u[k] << 16;
      hi.u = qa.u[k] & 0xFFFF0000u;
      acc[2 * k]     += wa * lo.f;
      acc[2 * k + 1] += wa * hi.f;
      lo.u = qb.u[k] << 16;
      hi.u = qb.u[k] & 0xFFFF0000u;
      acc[2 * k]     += wb * lo.f;
      acc[2 * k + 1] += wb * hi.f;
    }
  }
  #pragma unroll
  for (int k = 0; k < 8; k++) {
    acc[k] += __shfl_xor(acc[k], 16, 64);
    acc[k] += __shfl_xor(acc[k], 32, 64);
  }
  if (grp == 0) {
    float dc = dis[wid];
    unsigned short o[8] = {f2bf(acc[0] * dc), f2bf(acc[1] * dc), f2bf(acc[2] * dc),
                           f2bf(acc[3] * dc), f2bf(acc[4] * dc), f2bf(acc[5] * dc),
                           f2bf(acc[6] * dc), f2bf(acc[7] * dc)};
    *(uint4*)&yb[(size_t)wid * DD + l16 * 8] = *(uint4*)o;
  }
}

// ---- K4: fused GEMM: out = [xb | yb] @ WT2^T  (M=N, K=256, Nout=128) ----
__global__ __launch_bounds__(256) void k_gemm(const unsigned short* __restrict__ xb,
    const unsigned short* __restrict__ yb, const unsigned short* __restrict__ WT2,
    float* __restrict__ out, int N) {
  __shared__ __align__(16) unsigned short Bl[128 * 256]; // 64KB, swizzled (row = 512B)
  __shared__ __align__(16) unsigned short Al[64 * 256];  // 32KB, swizzled
  int t = threadIdx.x;
  int rowbase = blockIdx.x * 64;

  const uint4* WTv = (const uint4*)WT2;
  #pragma unroll
  for (int i = 0; i < 16; i++) {
    int ci = t + i * 256;            // 0..4095
    int j = ci >> 5, c16 = ci & 31;  // 32 chunks per row
    uint4 v = WTv[ci];
    int byte = j * 512 + c16 * 16;
    byte ^= (j & 7) << 4;
    *(uint4*)((char*)Bl + byte) = v;
  }
  #pragma unroll
  for (int i = 0; i < 8; i++) {
    int ci = t + i * 256;            // 0..2047
    int r = ci >> 5, c16 = ci & 31;
    int gr = rowbase + r;
    uint4 v = make_uint4(0, 0, 0, 0);
    if (gr < N) {
      if (c16 < 16) v = *(const uint4*)&xb[(size_t)gr * DD + c16 * 8];
      else          v = *(const uint4*)&yb[(size_t)gr * DD + (c16 - 16) * 8];
    }
    int byte = r * 512 + c16 * 16;
    byte ^= (r & 7) << 4;
    *(uint4*)((char*)Al + byte) = v;
  }
  __syncthreads();

  int wid = t >> 6, lane = t & 63;
  int wn = wid * 32;
  int l15 = lane & 15, l4 = lane >> 4;
  f32x4 acc[4][2] = {};
  #pragma unroll
  for (int kk = 0; kk < 8; kk++) {
    bf16x8 af[4], bfr[2];
    #pragma unroll
    for (int m = 0; m < 4; m++) {
      int r = m * 16 + l15;
      int byte = r * 512 + kk * 64 + l4 * 16;
      byte ^= (r & 7) << 4;
      af[m] = *(const bf16x8*)((const char*)Al + byte);
    }
    #pragma unroll
    for (int n = 0; n < 2; n++) {
      int r = wn + n * 16 + l15;
      int byte = r * 512 + kk * 64 + l4 * 16;
      byte ^= (r & 7) << 4;
      bfr[n] = *(const bf16x8*)((const char*)Bl + byte);
    }
    #pragma unroll
    for (int m = 0; m < 4; m++)
      #pragma unroll
      for (int n = 0; n < 2; n++)
        acc[m][n] = __builtin_amdgcn_mfma_f32_16x16x32_bf16(af[m], bfr[n], acc[m][n], 0, 0, 0);
  }

  #pragma unroll
  for (int m = 0; m < 4; m++) {
    int gr0 = rowbase + m * 16 + l4 * 4;
    #pragma unroll
    for (int n = 0; n < 2; n++) {
      int gc = wn + n * 16 + l15;
      #pragma unroll
      for (int j = 0; j < 4; j++) {
        int gr = gr0 + j;
        if (gr < N) out[(size_t)gr * DD + gc] = acc[m][n][j];
      }
    }
  }
}

extern "C" void kernel_launch(void* const* d_in, const int* in_sizes, int n_in,
                              void* d_out, int out_size, void* d_ws, size_t ws_size,
                              hipStream_t stream) {
  const float* x  = (const float*)d_in[0];
  const int*   ei = (const int*)d_in[1];
  const float* ew = (const float*)d_in[2];
  const float* Wl = (const float*)d_in[3];
  const float* Wg = (const float*)d_in[4];
  float* out = (float*)d_out;
  const int* row = ei;      // src
  const int* col = ei + NE; // dst

  char* base = (char*)d_ws;
  unsigned long long* degcnt = (unsigned long long*)base;               // NP u64 (zeroed)
  float* dis = (float*)(base + (size_t)NP * 8);                         // NP f32
  unsigned long long* edgeA = (unsigned long long*)(base + (size_t)NP * 12); // NP*CAP u64
  unsigned short* xb = (unsigned short*)((char*)edgeA + (size_t)NP * CAP * 8); // N*DD bf16
  unsigned short* yb = xb + (size_t)NN * DD;                            // N*DD bf16
  unsigned short* WT2 = yb + (size_t)NN * DD;                           // 128*256 bf16

  hipMemsetAsync(degcnt, 0, (size_t)NP * 8, stream);

  k_misc<<<MISC_BLKS, 256, 0, stream>>>(row, col, ew, x, Wl, Wg, degcnt, edgeA, xb, WT2);
  k_dis<<<(NN + 255) / 256, 256, 0, stream>>>(degcnt, dis);
  k_gather<<<(NN * 64 + 255) / 256, 256, 0, stream>>>(xb, degcnt, dis, edgeA, yb);
  k_gemm<<<(NN + 63) / 64, 256, 0, stream>>>(xb, yb, WT2, out, NN);
}

// Round 9
// 161.239 us; speedup vs baseline: 1.6734x; 1.6734x over previous
//
#include <hip/hip_runtime.h>

#define NN 100000
#define NE 1600000
#define DD 128
#define NB 1563          // ceil(NN/64) bins of 64 dsts
#define HIST_BLKS 256
#define CAST_BLKS 752
#define WT2_BLKS  16
#define K1_BLKS (HIST_BLKS + CAST_BLKS + WT2_BLKS)
#define BINCAP 1536      // mean bin load 1024, sigma 32 -> 16 sigma headroom

typedef __attribute__((ext_vector_type(8))) short bf16x8;
typedef __attribute__((ext_vector_type(4))) float f32x4;

__device__ inline unsigned short f2bf(float f) {
  union { float f; unsigned u; } v; v.f = f;
  unsigned r = (v.u + 0x7FFF + ((v.u >> 16) & 1)) >> 16;
  return (unsigned short)r;
}

// ---- KB1: per-block LDS histogram of dst>>6 (no global atomics) + x->bf16 cast + W transpose ----
__global__ __launch_bounds__(512) void kb1(const int* __restrict__ col,
    const float* __restrict__ x, const float* __restrict__ Wl, const float* __restrict__ Wg,
    unsigned* __restrict__ hist, unsigned short* __restrict__ xb, unsigned short* __restrict__ WT2) {
  __shared__ unsigned h1[NB];
  int b = blockIdx.x, tid = threadIdx.x;
  if (b < HIST_BLKS) {
    for (int i = tid; i < NB; i += 512) h1[i] = 0;
    __syncthreads();
    for (int e = b * 512 + tid; e < NE; e += HIST_BLKS * 512)
      atomicAdd(&h1[((unsigned)col[e]) >> 6], 1u);
    __syncthreads();
    for (int i = tid; i < NB; i += 512) hist[(size_t)i * HIST_BLKS + b] = h1[i]; // [bin][block]
  } else if (b < HIST_BLKS + CAST_BLKS) {
    int bb = b - HIST_BLKS;
    const int total8 = NN * DD / 8;
    for (int i = bb * 512 + tid; i < total8; i += CAST_BLKS * 512) {
      float4 a = *(const float4*)&x[i * 8];
      float4 q = *(const float4*)&x[i * 8 + 4];
      unsigned short o[8] = {f2bf(a.x), f2bf(a.y), f2bf(a.z), f2bf(a.w),
                             f2bf(q.x), f2bf(q.y), f2bf(q.z), f2bf(q.w)};
      *(uint4*)&xb[i * 8] = *(uint4*)o;
    }
  } else {
    int bb = b - HIST_BLKS - CAST_BLKS;   // 0..15
    int j = bb * 8 + (tid >> 6);          // 0..127
    int l = tid & 63;
    for (int k = l; k < 256; k += 64) {
      const float* W = (k < DD) ? Wl : Wg;
      WT2[j * 256 + k] = f2bf(W[(k & (DD - 1)) * DD + j]);
    }
  }
}

// ---- KB2a: per-bin totals (one wave per bin, coalesced row read) ----
__global__ __launch_bounds__(256) void kb2a(const unsigned* __restrict__ hist,
    unsigned* __restrict__ binTotal) {
  int w = (blockIdx.x * 256 + threadIdx.x) >> 6, l = threadIdx.x & 63;
  if (w >= NB) return;
  unsigned s = 0;
  for (int k = l; k < HIST_BLKS; k += 64) s += hist[(size_t)w * HIST_BLKS + k];
  #pragma unroll
  for (int off = 32; off >= 1; off >>= 1) s += __shfl_down(s, off, 64);
  if (l == 0) binTotal[w] = s;
}

// ---- KB2b: single-block exclusive scan of bin totals -> binBase[NB+1] ----
__global__ __launch_bounds__(512) void kb2b(const unsigned* __restrict__ binTotal,
    unsigned* __restrict__ binBase) {
  __shared__ unsigned ps[512];
  int t = threadIdx.x;
  unsigned v[4], s = 0;
  #pragma unroll
  for (int k = 0; k < 4; k++) { int i = t * 4 + k; v[k] = (i < NB) ? binTotal[i] : 0; s += v[k]; }
  ps[t] = s;
  __syncthreads();
  for (int off = 1; off < 512; off <<= 1) {
    unsigned u = (t >= off) ? ps[t - off] : 0;
    __syncthreads();
    ps[t] += u;
    __syncthreads();
  }
  unsigned run = ps[t] - s;
  #pragma unroll
  for (int k = 0; k < 4; k++) { int i = t * 4 + k; if (i < NB + 1) binBase[i] = run; run += v[k]; }
}

// ---- KB2c: per-bin exclusive prefix over blocks -> off[block][bin] ----
__global__ __launch_bounds__(256) void kb2c(const unsigned* __restrict__ hist,
    const unsigned* __restrict__ binBase, unsigned* __restrict__ off) {
  int w = (blockIdx.x * 256 + threadIdx.x) >> 6, l = threadIdx.x & 63;
  if (w >= NB) return;
  unsigned v[4], s = 0;
  #pragma unroll
  for (int k = 0; k < 4; k++) { v[k] = hist[(size_t)w * HIST_BLKS + l * 4 + k]; s += v[k]; }
  unsigned incl = s;
  #pragma unroll
  for (int o = 1; o < 64; o <<= 1) { unsigned tt = __shfl_up(incl, o, 64); if (l >= o) incl += tt; }
  unsigned run = binBase[w] + incl - s;
  #pragma unroll
  for (int k = 0; k < 4; k++) { off[(size_t)(l * 4 + k) * NB + w] = run; run += v[k]; }
}

// ---- KB3: atomic-free scatter into binned edge array (LDS replay of offsets) ----
// entry = w_bits(32) | src<<6 | dstlo(6)
__global__ __launch_bounds__(512) void kb3(const int* __restrict__ row, const int* __restrict__ col,
    const float* __restrict__ ew, const unsigned* __restrict__ off,
    unsigned long long* __restrict__ entries) {
  __shared__ unsigned cnt[NB];
  int b = blockIdx.x, tid = threadIdx.x;
  for (int i = tid; i < NB; i += 512) cnt[i] = off[(size_t)b * NB + i];
  __syncthreads();
  for (int e = b * 512 + tid; e < NE; e += HIST_BLKS * 512) {
    int c = col[e];
    unsigned pos = atomicAdd(&cnt[((unsigned)c) >> 6], 1u);
    entries[pos] = ((unsigned long long)__float_as_uint(ew[e]) << 32)
                 | ((unsigned)row[e] << 6) | (unsigned)(c & 63);
  }
}

// ---- KB4: weighted degree (LDS fixed-point, deterministic) -> dis ----
__global__ __launch_bounds__(256) void kb4(const unsigned long long* __restrict__ entries,
    const unsigned* __restrict__ binBase, float* __restrict__ dis) {
  __shared__ unsigned degFx[64];
  int bin = blockIdx.x, tid = threadIdx.x;
  if (tid < 64) degFx[tid] = 0;
  __syncthreads();
  unsigned s0 = binBase[bin], n = binBase[bin + 1] - s0;
  for (unsigned i = tid; i < n; i += 256) {
    unsigned long long e = entries[s0 + i];
    float w = __uint_as_float((unsigned)(e >> 32));
    atomicAdd(&degFx[(unsigned)e & 63], (unsigned)(w * 67108864.0f + 0.5f));
  }
  __syncthreads();
  if (tid < 64) {
    int node = bin * 64 + tid;
    if (node < NN) {
      float d = (float)degFx[tid] * (1.0f / 67108864.0f);
      dis[node] = (d > 0.0f) ? rsqrtf(d) : 0.0f;
    }
  }
}

// ---- KB5: per-bin gather: LDS counting-sort by exact dst, wn prefetch, R7 inner loop ----
__global__ __launch_bounds__(512) void kb5(const unsigned long long* __restrict__ entries,
    const unsigned* __restrict__ binBase, const float* __restrict__ dis,
    const unsigned short* __restrict__ xb, unsigned short* __restrict__ yb) {
  __shared__ unsigned long long raw[BINCAP], srt[BINCAP];
  __shared__ unsigned short rnk[BINCAP];
  __shared__ unsigned cnt64[64];
  __shared__ unsigned base64[64];
  int bin = blockIdx.x, tid = threadIdx.x;
  unsigned s0 = binBase[bin];
  int n = (int)(binBase[bin + 1] - s0);
  if (n > BINCAP) n = BINCAP;
  if (tid < 64) cnt64[tid] = 0;
  for (int i = tid; i < n; i += 512) raw[i] = entries[s0 + i];
  __syncthreads();
  for (int i = tid; i < n; i += 512)
    rnk[i] = (unsigned short)atomicAdd(&cnt64[(unsigned)raw[i] & 63], 1u);
  __syncthreads();
  if (tid < 64) { // wave 0: exclusive scan of per-dst counts
    unsigned v = cnt64[tid], incl = v;
    #pragma unroll
    for (int o = 1; o < 64; o <<= 1) { unsigned t2 = __shfl_up(incl, o, 64); if (tid >= o) incl += t2; }
    base64[tid] = incl - v;
  }
  __syncthreads();
  for (int i = tid; i < n; i += 512) {
    unsigned long long e = raw[i];
    srt[base64[(unsigned)e & 63] + rnk[i]] = e;
  }
  __syncthreads();
  // batched wn = w * dis[src] prefetch (high MLP on the random dis reads)
  for (int i = tid; i < n; i += 512) {
    unsigned long long e = srt[i];
    unsigned src = ((unsigned)e) >> 6;
    float wn = __uint_as_float((unsigned)(e >> 32)) * dis[src];
    srt[i] = ((unsigned long long)__float_as_uint(wn) << 32) | (unsigned)(e & 0xFFFFFFFFu);
  }
  __syncthreads();
  int wv = tid >> 6, lane = tid & 63, grp = lane >> 4, l16 = lane & 15;
  for (int dd = 0; dd < 8; ++dd) {
    int d = wv * 8 + dd;
    int c = bin * 64 + d;
    if (c >= NN) break;
    int e0 = base64[d], m = cnt64[d];
    float acc[8] = {};
    for (int i = 0; i < m; i += 8) {
      int ja = i + grp, jb = i + 4 + grp;
      unsigned sa = 0, sb = 0;
      float wa = 0.f, wb = 0.f;
      if (ja < m) { unsigned long long e = srt[e0 + ja]; sa = ((unsigned)e) >> 6; wa = __uint_as_float((unsigned)(e >> 32)); }
      if (jb < m) { unsigned long long e = srt[e0 + jb]; sb = ((unsigned)e) >> 6; wb = __uint_as_float((unsigned)(e >> 32)); }
      uint4 ha = *(const uint4*)&xb[(size_t)sa * DD + l16 * 8];
      uint4 hb = *(const uint4*)&xb[(size_t)sb * DD + l16 * 8];
      union { uint4 v; unsigned u[4]; } qa, qb;
      qa.v = ha; qb.v = hb;
      #pragma unroll
      for (int k = 0; k < 4; k++) {
        union { unsigned u; float f; } lo, hi;
        lo.u = qa.u[k] << 16;
        hi.u = qa.u[k] & 0xFFFF0000u;
        acc[2 * k]     += wa * lo.f;
        acc[2 * k + 1] += wa * hi.f;
        lo.u = qb.u[k] << 16;
        hi.u = qb.u[k] & 0xFFFF0000u;
        acc[2 * k]     += wb * lo.f;
        acc[2 * k + 1] += wb * hi.f;
      }
    }
    #pragma unroll
    for (int k = 0; k < 8; k++) {
      acc[k] += __shfl_xor(acc[k], 16, 64);
      acc[k] += __shfl_xor(acc[k], 32, 64);
    }
    if (grp == 0) {
      float dc = dis[c];
      unsigned short o[8] = {f2bf(acc[0] * dc), f2bf(acc[1] * dc), f2bf(acc[2] * dc),
                             f2bf(acc[3] * dc), f2bf(acc[4] * dc), f2bf(acc[5] * dc),
                             f2bf(acc[6] * dc), f2bf(acc[7] * dc)};
      *(uint4*)&yb[(size_t)c * DD + l16 * 8] = *(uint4*)o;
    }
  }
}

// ---- K4: fused GEMM: out = [xb | yb] @ WT2^T  (M=N, K=256, Nout=128) ----
__global__ __launch_bounds__(256) void k_gemm(const unsigned short* __restrict__ xb,
    const unsigned short* __restrict__ yb, const unsigned short* __restrict__ WT2,
    float* __restrict__ out, int N) {
  __shared__ __align__(16) unsigned short Bl[128 * 256]; // 64KB, swizzled (row = 512B)
  __shared__ __align__(16) unsigned short Al[64 * 256];  // 32KB, swizzled
  int t = threadIdx.x;
  int rowbase = blockIdx.x * 64;

  const uint4* WTv = (const uint4*)WT2;
  #pragma unroll
  for (int i = 0; i < 16; i++) {
    int ci = t + i * 256;
    int j = ci >> 5, c16 = ci & 31;
    uint4 v = WTv[ci];
    int byte = j * 512 + c16 * 16;
    byte ^= (j & 7) << 4;
    *(uint4*)((char*)Bl + byte) = v;
  }
  #pragma unroll
  for (int i = 0; i < 8; i++) {
    int ci = t + i * 256;
    int r = ci >> 5, c16 = ci & 31;
    int gr = rowbase + r;
    uint4 v = make_uint4(0, 0, 0, 0);
    if (gr < N) {
      if (c16 < 16) v = *(const uint4*)&xb[(size_t)gr * DD + c16 * 8];
      else          v = *(const uint4*)&yb[(size_t)gr * DD + (c16 - 16) * 8];
    }
    int byte = r * 512 + c16 * 16;
    byte ^= (r & 7) << 4;
    *(uint4*)((char*)Al + byte) = v;
  }
  __syncthreads();

  int wid = t >> 6, lane = t & 63;
  int wn = wid * 32;
  int l15 = lane & 15, l4 = lane >> 4;
  f32x4 acc[4][2] = {};
  #pragma unroll
  for (int kk = 0; kk < 8; kk++) {
    bf16x8 af[4], bfr[2];
    #pragma unroll
    for (int m = 0; m < 4; m++) {
      int r = m * 16 + l15;
      int byte = r * 512 + kk * 64 + l4 * 16;
      byte ^= (r & 7) << 4;
      af[m] = *(const bf16x8*)((const char*)Al + byte);
    }
    #pragma unroll
    for (int n = 0; n < 2; n++) {
      int r = wn + n * 16 + l15;
      int byte = r * 512 + kk * 64 + l4 * 16;
      byte ^= (r & 7) << 4;
      bfr[n] = *(const bf16x8*)((const char*)Bl + byte);
    }
    #pragma unroll
    for (int m = 0; m < 4; m++)
      #pragma unroll
      for (int n = 0; n < 2; n++)
        acc[m][n] = __builtin_amdgcn_mfma_f32_16x16x32_bf16(af[m], bfr[n], acc[m][n], 0, 0, 0);
  }

  #pragma unroll
  for (int m = 0; m < 4; m++) {
    int gr0 = rowbase + m * 16 + l4 * 4;
    #pragma unroll
    for (int n = 0; n < 2; n++) {
      int gc = wn + n * 16 + l15;
      #pragma unroll
      for (int j = 0; j < 4; j++) {
        int gr = gr0 + j;
        if (gr < N) out[(size_t)gr * DD + gc] = acc[m][n][j];
      }
    }
  }
}

extern "C" void kernel_launch(void* const* d_in, const int* in_sizes, int n_in,
                              void* d_out, int out_size, void* d_ws, size_t ws_size,
                              hipStream_t stream) {
  const float* x  = (const float*)d_in[0];
  const int*   ei = (const int*)d_in[1];
  const float* ew = (const float*)d_in[2];
  const float* Wl = (const float*)d_in[3];
  const float* Wg = (const float*)d_in[4];
  float* out = (float*)d_out;
  const int* row = ei;      // src
  const int* col = ei + NE; // dst

  const size_t MB = 1u << 20;
  char* base = (char*)d_ws;
  unsigned* hist     = (unsigned*)(base);                 // 1.6MB  [bin][block]
  unsigned* off      = (unsigned*)(base + 2 * MB);        // 1.6MB  [block][bin]
  unsigned* binTotal = (unsigned*)(base + 4 * MB);        // 8KB
  unsigned* binBase  = (unsigned*)(base + 4 * MB + 32768);// 8KB (NB+1 used)
  unsigned long long* entries = (unsigned long long*)(base + 5 * MB);  // 12.8MB
  float* dis = (float*)(base + 18 * MB);                  // 400KB
  unsigned short* xb = (unsigned short*)(base + 19 * MB); // 25.6MB
  unsigned short* yb = (unsigned short*)(base + 45 * MB); // 25.6MB
  unsigned short* WT2 = (unsigned short*)(base + 71 * MB);// 64KB

  kb1<<<K1_BLKS, 512, 0, stream>>>(col, x, Wl, Wg, hist, xb, WT2);
  kb2a<<<(NB + 3) / 4, 256, 0, stream>>>(hist, binTotal);
  kb2b<<<1, 512, 0, stream>>>(binTotal, binBase);
  kb2c<<<(NB + 3) / 4, 256, 0, stream>>>(hist, binBase, off);
  kb3<<<HIST_BLKS, 512, 0, stream>>>(row, col, ew, off, entries);
  kb4<<<NB, 256, 0, stream>>>(entries, binBase, dis);
  kb5<<<NB, 512, 0, stream>>>(entries, binBase, dis, xb, yb);
  k_gemm<<<(NN + 63) / 64, 256, 0, stream>>>(xb, yb, WT2, out, NN);
}